// Round 2
// baseline (5030.256 us; speedup 1.0000x reference)
//
#include <hip/hip_runtime.h>
#include <stdint.h>

// Seq2seq GRU encoder + greedy GRU decoder, single persistent cooperative kernel.
// R4 changes vs R3 (latency-structural; data movement unchanged):
//  - Flat monotonic-counter grid barrier: one fetch_add + poll (2 IC RTs vs 4
//    for the old 3-level tree). No resets, epochs tracked per-block.
//  - Split arrive/wait with overlap zones:
//      * encoder: ih-dots (W_ih @ x, token known ahead) for step t+1 computed
//        while waiting on barrier t. Post-release path = load h -> hh-dots ->
//        combine -> store -> arrive.
//      * decoder: hh-dots (W_hh @ h) for step t+1 computed in the S2 wait
//        window (h already in LDS). Post-S2 path = gkey+gsum (1 RT, issued
//        together) -> dec_emb row -> ih-dots -> store -> S1.
//  - dec_emb[tok] row load issued immediately after nxt is known.
// Math is bit-identical to R3 (dot accumulation order unchanged).

#define HID 1024
#define SRC_LEN 256
#define MAX_LEN 128
#define VOC 32000
#define EOS_TOK 2u

#define NBLK 256
#define NTHR 256
#define RPB 125            // vocab rows per block = 32000/256

// ---- workspace layout (bytes) ----
#define WS_CNT    0        // u32 monotonic barrier counter
#define WS_GSUM   2048     // u64[128] fixed-point softmax sums
#define WS_GKEY   3072     // u64[128] argmax keys
#define WS_HB     4096     // float[2][1024] double-buffered h
#define WS_EXP    12288    // float[32000] exp(logit)   (same-block only)
#define WS_ZERO   12288    // bytes to memset each call

#define A_SCOPE __HIP_MEMORY_SCOPE_AGENT

#if __has_builtin(__builtin_amdgcn_cvt_pk_f32_fp8) && __has_builtin(__builtin_amdgcn_cvt_pk_fp8_f32)
#define USE_HW_FP8 1
#else
#define USE_HW_FP8 0
#endif

typedef float v2f __attribute__((ext_vector_type(2)));

__device__ inline unsigned ld_a32(const unsigned* p) {
  return __hip_atomic_load((unsigned*)p, __ATOMIC_RELAXED, A_SCOPE);
}
__device__ inline unsigned long long ld_a64(const unsigned long long* p) {
  return __hip_atomic_load((unsigned long long*)p, __ATOMIC_RELAXED, A_SCOPE);
}
__device__ inline void st_af(float* p, float v) {
  __hip_atomic_store(p, v, __ATOMIC_RELAXED, A_SCOPE);
}

__device__ inline float sigm(float x) { return 1.0f / (1.0f + __expf(-x)); }

// ---- fp8 e4m3fn helpers (values pre-scaled by 256; enc/dec always paired) ----
__device__ inline unsigned fp8_enc1(float v) {
  const unsigned u = __float_as_uint(v);
  const unsigned s = u >> 31;
  unsigned a = u & 0x7FFFFFFFu;
  if (a < 0x3C800000u) return 0u;          // |v| < 2^-6 -> flush to 0
  a += ((a >> 20) & 1u) + 0x7FFFFu;        // RNE to 3 mantissa bits
  const unsigned e = (a >> 23) - 120u;     // inputs bounded (<32): e in 1..15
  return (s << 7) | (e << 3) | ((a >> 20) & 7u);
}
__device__ inline unsigned fp8x4_enc(float4 f) {
#if USE_HW_FP8
  int v = __builtin_amdgcn_cvt_pk_fp8_f32(f.x, f.y, 0, false);
  v = __builtin_amdgcn_cvt_pk_fp8_f32(f.z, f.w, v, true);
  return (unsigned)v;
#else
  return fp8_enc1(f.x) | (fp8_enc1(f.y) << 8) |
         (fp8_enc1(f.z) << 16) | (fp8_enc1(f.w) << 24);
#endif
}
__device__ inline float fp8_dec1(unsigned q) {
  const unsigned m = q & 0x7Fu;
  return m ? __uint_as_float(((m << 20) + 0x3C000000u) | ((q & 0x80u) << 24)) : 0.0f;
}

// ---- flat monotonic barrier: arrive (fetch_add) / wait (poll >= ep*NBLK) ----
__device__ inline void bar_arrive(char* ws) {
  __syncthreads();                       // all waves drain stores (vmcnt0/barrier)
  if (threadIdx.x == 0) {
    __atomic_signal_fence(__ATOMIC_SEQ_CST);
    __builtin_amdgcn_s_waitcnt(0);       // drain thread0's own stores/atomics
    __hip_atomic_fetch_add((unsigned*)(ws + WS_CNT), 1u, __ATOMIC_RELAXED, A_SCOPE);
  }
}
__device__ inline void bar_wait(char* ws, unsigned ep) {
  if (threadIdx.x == 0) {
    const unsigned tgt = ep * NBLK;
    while ((int)(ld_a32((unsigned*)(ws + WS_CNT)) - tgt) < 0)
      __builtin_amdgcn_s_sleep(1);
    __atomic_signal_fence(__ATOMIC_SEQ_CST);
  }
  __syncthreads();
}

// stage 4KB h vector from ws into LDS via coherent u64 loads
__device__ inline void load_h_lds(float* dst, const float* src, int tid) {
  const unsigned long long* s = (const unsigned long long*)src;
  unsigned long long* d = (unsigned long long*)dst;
  const unsigned long long a = ld_a64(s + 2 * tid);
  const unsigned long long b = ld_a64(s + 2 * tid + 1);
  d[2 * tid] = a;
  d[2 * tid + 1] = b;
}

// three 1024-dots of rows r0,r1,r2 against LDS vector v; result in all lanes
__device__ inline void dots3(const float* __restrict__ r0, const float* __restrict__ r1,
                             const float* __restrict__ r2, int lane,
                             const float* __restrict__ v,
                             float& d0, float& d1, float& d2) {
  float a0 = 0.f, a1 = 0.f, a2 = 0.f;
#pragma unroll
  for (int i = 0; i < 8; ++i) {
    const int e = 2 * lane + 128 * i;
    const float2 xv = *(const float2*)(v + e);
    float2 w;
    w = *(const float2*)(r0 + e); a0 += w.x * xv.x + w.y * xv.y;
    w = *(const float2*)(r1 + e); a1 += w.x * xv.x + w.y * xv.y;
    w = *(const float2*)(r2 + e); a2 += w.x * xv.x + w.y * xv.y;
  }
#pragma unroll
  for (int off = 32; off; off >>= 1) {
    a0 += __shfl_xor(a0, off); a1 += __shfl_xor(a1, off); a2 += __shfl_xor(a2, off);
  }
  d0 = a0; d1 = a1; d2 = a2;
}

__device__ inline float gru_comb(float ai0, float ai1, float ai2,
                                 float ah0, float ah1, float ah2,
                                 float bi0, float bi1, float bi2,
                                 float bh0, float bh1, float bh2, float hold) {
  const float r = sigm(ai0 + bi0 + ah0 + bh0);
  const float z = sigm(ai1 + bi1 + ah1 + bh1);
  const float n = tanhf(ai2 + bi2 + r * (ah2 + bh2));
  return (1.f - z) * n + z * hold;
}

__global__ void __launch_bounds__(NTHR)
seq2seq_kernel(const int* __restrict__ X,
               const float* __restrict__ enc_emb,
               const float* __restrict__ enc_wih, const float* __restrict__ enc_whh,
               const float* __restrict__ enc_bih, const float* __restrict__ enc_bhh,
               const float* __restrict__ dec_emb,
               const float* __restrict__ dec_wih, const float* __restrict__ dec_whh,
               const float* __restrict__ dec_bih, const float* __restrict__ dec_bhh,
               const float* __restrict__ lin_w, const float* __restrict__ lin_b,
               float* __restrict__ out, char* __restrict__ ws) {
  __shared__ float sx[HID];
  __shared__ float sh[HID];
  __shared__ float spart[256];
  __shared__ float slog[128];
  __shared__ float redS[4];
  __shared__ float sbmax;
  __shared__ unsigned long long sball[2];
  // time-shared 128 KB region:
  //   encoder phase: f32 wenc[4][6][1024]   (96 KB)
  //   decode phase : u64 lq[128 k8][128 r]  (128 KB) fp8 e4m3fn x256 lin_w rows
  __shared__ __align__(16) unsigned char dynls[131072];

  const int b = blockIdx.x, tid = threadIdx.x;
  const int q = tid >> 6, lane = tid & 63;
  const int j = 4 * b + q;
  const int vbase = b * RPB;

  unsigned long long* gsum = (unsigned long long*)(ws + WS_GSUM);
  unsigned long long* gkey = (unsigned long long*)(ws + WS_GKEY);
  float* hb = (float*)(ws + WS_HB);
  float* expb = (float*)(ws + WS_EXP);
  float* probs = out + (MAX_LEN + 1);

  unsigned ep = 0;   // barrier epoch (uniform across blocks)

  // per-wave biases for hidden unit j (gates r,z,n stacked at 0,H,2H)
  float ebi0 = enc_bih[j], ebi1 = enc_bih[HID + j], ebi2 = enc_bih[2 * HID + j];
  float ebh0 = enc_bhh[j], ebh1 = enc_bhh[HID + j], ebh2 = enc_bhh[2 * HID + j];
  float dbi0 = dec_bih[j], dbi1 = dec_bih[HID + j], dbi2 = dec_bih[2 * HID + j];
  float dbh0 = dec_bhh[j], dbh1 = dec_bhh[HID + j], dbh2 = dec_bhh[2 * HID + j];

  if (b == 0 && tid == 0) out[0] = 1.0f;  // SOS

  // ---- P0: stage this block's 24 encoder GRU rows into LDS (f32) ----
  {
    float* wenc = (float*)dynls;
    for (int rr = 0; rr < 24; ++rr) {      // rr = q*6 + g, g in {ih r,z,n, hh r,z,n}
      const int qq = rr / 6, g = rr % 6;
      const int jj = 4 * b + qq;
      const float* src = (g < 3)
          ? (enc_wih + (size_t)(g * HID + jj) * HID)
          : (enc_whh + (size_t)((g - 3) * HID + jj) * HID);
      ((float4*)(wenc + rr * HID))[tid] = ((const float4*)src)[tid];
    }
  }
  bar_arrive(ws); ++ep; bar_wait(ws, ep);

  // ---- encoder: 256 sequential GRU steps, software-pipelined ----
  {
    const float* wq = (const float*)dynls + q * 6 * HID;
    // prologue: stage x0, ih-dots for t=0, prefetch x1
    float4 pf = ((const float4*)(enc_emb + (size_t)X[0] * HID))[tid];
    ((float4*)sx)[tid] = pf;
    __syncthreads();
    float ri0, ri1, ri2;
    dots3(wq, wq + HID, wq + 2 * HID, lane, sx, ri0, ri1, ri2);
    pf = ((const float4*)(enc_emb + (size_t)X[1] * HID))[tid];

    for (int t = 0; t < SRC_LEN; ++t) {
      // h_{t-1} released by barrier ep (t=0: zeros from memset)
      load_h_lds(sh, hb + (t & 1) * HID, tid);
      __syncthreads();
      const float hold = sh[j];
      float rh0, rh1, rh2;
      dots3(wq + 3 * HID, wq + 4 * HID, wq + 5 * HID, lane, sh, rh0, rh1, rh2);
      const float hnew = gru_comb(ri0, ri1, ri2, rh0, rh1, rh2,
                                  ebi0, ebi1, ebi2, ebh0, ebh1, ebh2, hold);
      if (lane == 0) st_af(&hb[((t + 1) & 1) * HID + j], hnew);
      bar_arrive(ws); ++ep;
      // overlap zone: stage x_{t+1}, ih-dots(t+1), prefetch x_{t+2}
      if (t + 1 < SRC_LEN) {
        ((float4*)sx)[tid] = pf;
        __syncthreads();
        dots3(wq, wq + HID, wq + 2 * HID, lane, sx, ri0, ri1, ri2);
        if (t + 2 < SRC_LEN)
          pf = ((const float4*)(enc_emb + (size_t)X[t + 2] * HID))[tid];
      }
      bar_wait(ws, ep);
    }
  }

  // ---- P1: fp8 (e4m3fn, x256) transposed copy of this block's lin_w rows ----
  // layout: lq[k8][r] u64 = 8 fp8 (k = 8*k8..8*k8+7) of row vbase+r.
  {
    unsigned* lq32 = (unsigned*)dynls;
    const int k8 = tid >> 1, kh = tid & 1;   // thread covers cols 4*tid..4*tid+3
    for (int rr = 0; rr < RPB; ++rr) {
      float4 f = ((const float4*)(lin_w + (size_t)(vbase + rr) * HID))[tid];
      f.x *= 256.f; f.y *= 256.f; f.z *= 256.f; f.w *= 256.f;
      lq32[(size_t)(k8 * 128 + rr) * 2 + kh] = fp8x4_enc(f);
    }
    unsigned long long* lqz = (unsigned long long*)dynls;
    for (int i = tid; i < 3 * 128; i += NTHR)        // zero pad rows 125..127
      lqz[(i / 3) * 128 + 125 + (i % 3)] = 0ull;
  }
  __syncthreads();

  // ---- greedy decoder ----
  unsigned tok = 1u;   // SOS
  bool done = false;
  const unsigned long long* lq = (const unsigned long long*)dynls;

  // dec GRU row pointers for hidden unit j
  const float* di0 = dec_wih + (size_t)j * HID;
  const float* di1 = dec_wih + (size_t)(HID + j) * HID;
  const float* di2 = dec_wih + (size_t)(2 * HID + j) * HID;
  const float* dh0 = dec_whh + (size_t)j * HID;
  const float* dh1 = dec_whh + (size_t)(HID + j) * HID;
  const float* dh2 = dec_whh + (size_t)(2 * HID + j) * HID;

  // pre-loop: h_enc -> sh, hh-dots for t=0, x row for SOS
  load_h_lds(sh, hb, tid);                // h_enc in hb[0] (SRC_LEN even)
  __syncthreads();
  float rh0, rh1, rh2, hold;
  dots3(dh0, dh1, dh2, lane, sh, rh0, rh1, rh2);
  hold = sh[j];
  float4 xf = ((const float4*)(dec_emb + (size_t)tok * HID))[tid];

  for (int t = 0; t <= MAX_LEN; ++t) {
    if (t > 0) {
      // issue both IC loads back-to-back, then the x row load ASAP
      const unsigned long long key = ld_a64(&gkey[t - 1]);
      const unsigned long long sraw = ld_a64(&gsum[t - 1]);
      const unsigned nxt = 0xFFFFFFFFu - (unsigned)(key & 0xFFFFFFFFull);
      const unsigned ntok = done ? tok : nxt;
      xf = ((const float4*)(dec_emb + (size_t)ntok * HID))[tid];
      if (b == 0 && tid == 0) out[t] = done ? (float)EOS_TOK : (float)nxt;
      if (tid < RPB) {
        float p = 0.f;
        if (!done) {
          const double s = (double)sraw * (1.0 / 16777216.0);
          p = expb[vbase + tid] * (float)(1.0 / s);
        }
        probs[(size_t)(t - 1) * VOC + vbase + tid] = p;
      }
      tok = ntok;
      done = done || (nxt == EOS_TOK);
    }
    if (t == MAX_LEN) break;
    if (done) {
      for (int s = t; s < MAX_LEN; ++s) {
        if (tid < RPB) probs[(size_t)s * VOC + vbase + tid] = 0.f;
        if (b == 0 && tid == 0) out[s + 1] = (float)EOS_TOK;
      }
      break;
    }

    // ---- phase A: GRU cell on x = relu(dec_emb[tok]); hh-dots precomputed ----
    {
      float4 f = xf;
      f.x = fmaxf(f.x, 0.f); f.y = fmaxf(f.y, 0.f);
      f.z = fmaxf(f.z, 0.f); f.w = fmaxf(f.w, 0.f);
      ((float4*)sx)[tid] = f;
    }
    __syncthreads();
    float ai0, ai1, ai2;
    dots3(di0, di1, di2, lane, sx, ai0, ai1, ai2);
    const float hnew = gru_comb(ai0, ai1, ai2, rh0, rh1, rh2,
                                dbi0, dbi1, dbi2, dbh0, dbh1, dbh2, hold);
    if (lane == 0) st_af(&hb[((t + 1) & 1) * HID + j], hnew);
    bar_arrive(ws); ++ep;      // S1: h_new visible everywhere
    bar_wait(ws, ep);

    // ---- phase B: logits for this block's 125 vocab rows (fp8 from LDS) ----
    load_h_lds(sh, hb + ((t + 1) & 1) * HID, tid);
    if (tid < 128) slog[tid] = -1e30f;
    __syncthreads();

    {
      // two threads per row: r = tid&127 handles k-half kh = tid>>7
      const int r = tid & 127, kh = tid >> 7;
      const unsigned long long* wp = lq + ((size_t)kh << 13) + r;  // kh*64*128
      const float* hp = sh + (kh << 9);
      float acc = 0.f;
#pragma unroll 8
      for (int jj = 0; jj < 64; ++jj) {
        const unsigned long long w = wp[(size_t)jj << 7];
        const float4 h0 = *(const float4*)(hp + (jj << 3));
        const float4 h1 = *(const float4*)(hp + (jj << 3) + 4);
        const unsigned lo = (unsigned)w, hi = (unsigned)(w >> 32);
#if USE_HW_FP8
        const v2f f01 = __builtin_amdgcn_cvt_pk_f32_fp8(lo, false);
        const v2f f23 = __builtin_amdgcn_cvt_pk_f32_fp8(lo, true);
        const v2f f45 = __builtin_amdgcn_cvt_pk_f32_fp8(hi, false);
        const v2f f67 = __builtin_amdgcn_cvt_pk_f32_fp8(hi, true);
        acc += f01.x * h0.x + f01.y * h0.y + f23.x * h0.z + f23.y * h0.w
             + f45.x * h1.x + f45.y * h1.y + f67.x * h1.z + f67.y * h1.w;
#else
        acc += fp8_dec1(lo) * h0.x + fp8_dec1(lo >> 8) * h0.y
             + fp8_dec1(lo >> 16) * h0.z + fp8_dec1(lo >> 24) * h0.w
             + fp8_dec1(hi) * h1.x + fp8_dec1(hi >> 8) * h1.y
             + fp8_dec1(hi >> 16) * h1.z + fp8_dec1(hi >> 24) * h1.w;
#endif
      }
      spart[tid] = acc;
    }
    __syncthreads();
    float e = 0.f;
    if (tid < RPB) {
      const float logit = (spart[tid] + spart[tid + 128]) * (1.f / 256.f)
                        + lin_b[vbase + tid];
      e = __expf(logit);
      expb[vbase + tid] = e;
      slog[tid] = logit;
    }
    float s = e;
#pragma unroll
    for (int off = 32; off; off >>= 1) s += __shfl_xor(s, off);
    if (lane == 0) redS[q] = s;
    __syncthreads();

    // block-local max of approx logits
    if (q == 0) {
      float m = fmaxf(slog[lane], slog[lane + 64]);
#pragma unroll
      for (int off = 32; off; off >>= 1) m = fmaxf(m, __shfl_xor(m, off));
      if (lane == 0) sbmax = m;
    }
    __syncthreads();
    {
      const bool cand = (tid < RPB) && (slog[tid] >= sbmax - 4e-3f);
      const unsigned long long bal = __ballot(cand);
      if (lane == 0 && q < 2) sball[q] = bal;
    }
    __syncthreads();
    // exact-f32 re-check of candidate rows -> global argmax key
    {
      unsigned long long m0 = sball[0], m1 = sball[1];
      unsigned long long bestk = 0ull;
      int c = 0;
      while (m0 | m1) {
        int r;
        if (m0) { r = __ffsll(m0) - 1; m0 &= m0 - 1; }
        else    { r = 64 + __ffsll(m1) - 1; m1 &= m1 - 1; }
        if ((c & 3) == q) {
          const int v = vbase + r;
          const float* wr = lin_w + (size_t)v * HID;
          float acc = 0.f;
#pragma unroll
          for (int i = 0; i < 4; ++i) {
            const float4 f = *(const float4*)(wr + 4 * lane + 256 * i);
            const float4 hv = *(const float4*)(sh + 4 * lane + 256 * i);
            acc += f.x * hv.x + f.y * hv.y + f.z * hv.z + f.w * hv.w;
          }
#pragma unroll
          for (int off = 32; off; off >>= 1) acc += __shfl_xor(acc, off);
          const float logit = acc + lin_b[v];
          const unsigned u = __float_as_uint(logit);
          const unsigned sb = (u & 0x80000000u) ? ~u : (u | 0x80000000u);
          const unsigned long long k =
              ((unsigned long long)sb << 32) | (unsigned long long)(0xFFFFFFFFu - (unsigned)v);
          if (k > bestk) bestk = k;
        }
        ++c;
      }
      if (lane == 0 && bestk) atomicMax(&gkey[t], bestk);
    }
    if (tid == 0) {
      const float st = redS[0] + redS[1] + redS[2] + redS[3];
      atomicAdd(&gsum[t], (unsigned long long)((double)st * 16777216.0));
    }
    bar_arrive(ws); ++ep;      // S2: argmax key + sum globally visible
    // overlap zone: hh-dots for step t+1 (sh holds h_{t+1}, stable until next
    // phase B). Hides the W_hh work under the barrier release latency.
    dots3(dh0, dh1, dh2, lane, sh, rh0, rh1, rh2);
    hold = sh[j];
    bar_wait(ws, ep);
  }
}

extern "C" void kernel_launch(void* const* d_in, const int* in_sizes, int n_in,
                              void* d_out, int out_size, void* d_ws, size_t ws_size,
                              hipStream_t stream) {
  const int* X = (const int*)d_in[0];
  const float* enc_emb = (const float*)d_in[1];
  const float* enc_wih = (const float*)d_in[2];
  const float* enc_whh = (const float*)d_in[3];
  const float* enc_bih = (const float*)d_in[4];
  const float* enc_bhh = (const float*)d_in[5];
  const float* dec_emb = (const float*)d_in[6];
  const float* dec_wih = (const float*)d_in[7];
  const float* dec_whh = (const float*)d_in[8];
  const float* dec_bih = (const float*)d_in[9];
  const float* dec_bhh = (const float*)d_in[10];
  const float* lin_w = (const float*)d_in[11];
  const float* lin_b = (const float*)d_in[12];
  float* out = (float*)d_out;
  char* ws = (char*)d_ws;

  hipMemsetAsync(d_ws, 0, WS_ZERO, stream);
  void* args[] = { &X, &enc_emb, &enc_wih, &enc_whh, &enc_bih, &enc_bhh,
                   &dec_emb, &dec_wih, &dec_whh, &dec_bih, &dec_bhh,
                   &lin_w, &lin_b, &out, &ws };
  hipLaunchCooperativeKernel((void*)seq2seq_kernel, dim3(NBLK), dim3(NTHR),
                             args, 0, stream);
}

// Round 3
// 2620.727 us; speedup vs baseline: 1.9194x; 1.9194x over previous
//
#include <hip/hip_runtime.h>
#include <stdint.h>

// Seq2seq GRU encoder + greedy GRU decoder, single persistent cooperative kernel.
// R5: barrier-FREE tagged dataflow (R4's flat counter serialized 256 RMWs on one
// IC line -> regression; R3's tree cost 4 chained RTs per step).
//  - Every cross-block value is a tagged u64 {tag:32 | payload:32}, published
//    with one relaxed agent store, double-buffered by step parity. Consumers
//    poll only the words they need until tag matches. No grid barriers, no
//    contended atomics anywhere in steady state.
//  - h exchange: u64 ht[2][1024]; h_0 = zeros tag 0 straight from memset.
//  - softmax sum / argmax key: per-block slotted publishes (sums/keya/keyb
//    [2][256]) + deterministic in-block shuffle reduce (replaces the
//    256-serialized atomicAdd/atomicMax chains; bit-identical across blocks).
//  - Parity-2 reuse is safe: tag k+2 overwrites tag k only after every block
//    consumed tag k (transitive through the k+1 publish).
// Weights layout unchanged from R3/R4: enc GRU rows f32 in LDS, lin_w rows
// fp8 e4m3fn x256 in LDS, dec GRU rows from L2, exact-f32 argmax recheck.

#define HID 1024
#define SRC_LEN 256
#define MAX_LEN 128
#define VOC 32000
#define EOS_TOK 2u

#define NBLK 256
#define NTHR 256
#define RPB 125            // vocab rows per block = 32000/256

// ---- workspace layout (bytes) ----
#define WS_HT    0         // u64[2][1024] tagged h: low32 f32 bits, high32 tag
#define WS_SUM   16384     // u64[2][256]  low32 f32 partial-sum bits, high32 tag
#define WS_KEYA  20480     // u64[2][256]  low32 sortable-logit bits, high32 tag
#define WS_KEYB  24576     // u64[2][256]  low32 vocab-inv bits, high32 tag
#define WS_EXP   28672     // float[32000] exp(logit)  (same-block reuse only)
#define WS_ZERO  28672     // bytes to memset each call (covers all tagged slots)

#define A_SCOPE __HIP_MEMORY_SCOPE_AGENT

#if __has_builtin(__builtin_amdgcn_cvt_pk_f32_fp8) && __has_builtin(__builtin_amdgcn_cvt_pk_fp8_f32)
#define USE_HW_FP8 1
#else
#define USE_HW_FP8 0
#endif

typedef float v2f __attribute__((ext_vector_type(2)));

__device__ inline unsigned long long ld_a64(const unsigned long long* p) {
  return __hip_atomic_load((unsigned long long*)p, __ATOMIC_RELAXED, A_SCOPE);
}
__device__ inline void st_a64(unsigned long long* p, unsigned long long v) {
  __hip_atomic_store(p, v, __ATOMIC_RELAXED, A_SCOPE);
}

__device__ inline float sigm(float x) { return 1.0f / (1.0f + __expf(-x)); }

// ---- fp8 e4m3fn helpers (values pre-scaled by 256; enc/dec always paired) ----
__device__ inline unsigned fp8_enc1(float v) {
  const unsigned u = __float_as_uint(v);
  const unsigned s = u >> 31;
  unsigned a = u & 0x7FFFFFFFu;
  if (a < 0x3C800000u) return 0u;          // |v| < 2^-6 -> flush to 0
  a += ((a >> 20) & 1u) + 0x7FFFFu;        // RNE to 3 mantissa bits
  const unsigned e = (a >> 23) - 120u;     // inputs bounded (<32): e in 1..15
  return (s << 7) | (e << 3) | ((a >> 20) & 7u);
}
__device__ inline unsigned fp8x4_enc(float4 f) {
#if USE_HW_FP8
  int v = __builtin_amdgcn_cvt_pk_fp8_f32(f.x, f.y, 0, false);
  v = __builtin_amdgcn_cvt_pk_fp8_f32(f.z, f.w, v, true);
  return (unsigned)v;
#else
  return fp8_enc1(f.x) | (fp8_enc1(f.y) << 8) |
         (fp8_enc1(f.z) << 16) | (fp8_enc1(f.w) << 24);
#endif
}
__device__ inline float fp8_dec1(unsigned q) {
  const unsigned m = q & 0x7Fu;
  return m ? __uint_as_float(((m << 20) + 0x3C000000u) | ((q & 0x80u) << 24)) : 0.0f;
}

// gather full tagged h (1024 u64) into LDS f32[1024]; each thread polls 4 words
__device__ inline void gather_h(float* __restrict__ sh,
                                const unsigned long long* __restrict__ buf,
                                unsigned tg, int tid) {
  const unsigned long long* p = buf + 4 * (size_t)tid;
  unsigned long long a = ld_a64(p),     b = ld_a64(p + 1),
                     c = ld_a64(p + 2), d = ld_a64(p + 3);
  while ((((unsigned)(a >> 32)) != tg) | (((unsigned)(b >> 32)) != tg) |
         (((unsigned)(c >> 32)) != tg) | (((unsigned)(d >> 32)) != tg)) {
    __builtin_amdgcn_s_sleep(1);
    if (((unsigned)(a >> 32)) != tg) a = ld_a64(p);
    if (((unsigned)(b >> 32)) != tg) b = ld_a64(p + 1);
    if (((unsigned)(c >> 32)) != tg) c = ld_a64(p + 2);
    if (((unsigned)(d >> 32)) != tg) d = ld_a64(p + 3);
  }
  float4 v;
  v.x = __uint_as_float((unsigned)a);
  v.y = __uint_as_float((unsigned)b);
  v.z = __uint_as_float((unsigned)c);
  v.w = __uint_as_float((unsigned)d);
  ((float4*)sh)[tid] = v;
}

// three 1024-dots of rows r0,r1,r2 against LDS vector v; result in all lanes
__device__ inline void dots3(const float* __restrict__ r0, const float* __restrict__ r1,
                             const float* __restrict__ r2, int lane,
                             const float* __restrict__ v,
                             float& d0, float& d1, float& d2) {
  float a0 = 0.f, a1 = 0.f, a2 = 0.f;
#pragma unroll
  for (int i = 0; i < 8; ++i) {
    const int e = 2 * lane + 128 * i;
    const float2 xv = *(const float2*)(v + e);
    float2 w;
    w = *(const float2*)(r0 + e); a0 += w.x * xv.x + w.y * xv.y;
    w = *(const float2*)(r1 + e); a1 += w.x * xv.x + w.y * xv.y;
    w = *(const float2*)(r2 + e); a2 += w.x * xv.x + w.y * xv.y;
  }
#pragma unroll
  for (int off = 32; off; off >>= 1) {
    a0 += __shfl_xor(a0, off); a1 += __shfl_xor(a1, off); a2 += __shfl_xor(a2, off);
  }
  d0 = a0; d1 = a1; d2 = a2;
}

__device__ inline float gru_comb(float ai0, float ai1, float ai2,
                                 float ah0, float ah1, float ah2,
                                 float bi0, float bi1, float bi2,
                                 float bh0, float bh1, float bh2, float hold) {
  const float r = sigm(ai0 + bi0 + ah0 + bh0);
  const float z = sigm(ai1 + bi1 + ah1 + bh1);
  const float n = tanhf(ai2 + bi2 + r * (ah2 + bh2));
  return (1.f - z) * n + z * hold;
}

__global__ void __launch_bounds__(NTHR)
seq2seq_kernel(const int* __restrict__ X,
               const float* __restrict__ enc_emb,
               const float* __restrict__ enc_wih, const float* __restrict__ enc_whh,
               const float* __restrict__ enc_bih, const float* __restrict__ enc_bhh,
               const float* __restrict__ dec_emb,
               const float* __restrict__ dec_wih, const float* __restrict__ dec_whh,
               const float* __restrict__ dec_bih, const float* __restrict__ dec_bhh,
               const float* __restrict__ lin_w, const float* __restrict__ lin_b,
               float* __restrict__ out, char* __restrict__ ws) {
  __shared__ float sx[HID];
  __shared__ float sh[HID];
  __shared__ float spart[256];
  __shared__ float slog[128];
  __shared__ float redS[4];
  __shared__ float sbmax;
  __shared__ unsigned long long sball[2];
  __shared__ unsigned long long sbk[4];
  // time-shared 128 KB region:
  //   encoder phase: f32 wenc[4][6][1024]   (96 KB)
  //   decode phase : u64 lq[128 k8][128 r]  (128 KB) fp8 e4m3fn x256 lin_w rows
  __shared__ __align__(16) unsigned char dynls[131072];

  const int b = blockIdx.x, tid = threadIdx.x;
  const int q = tid >> 6, lane = tid & 63;
  const int j = 4 * b + q;
  const int vbase = b * RPB;

  unsigned long long* ht   = (unsigned long long*)(ws + WS_HT);
  unsigned long long* sums = (unsigned long long*)(ws + WS_SUM);
  unsigned long long* keya = (unsigned long long*)(ws + WS_KEYA);
  unsigned long long* keyb = (unsigned long long*)(ws + WS_KEYB);
  float* expb = (float*)(ws + WS_EXP);
  float* probs = out + (MAX_LEN + 1);

  // per-wave biases for hidden unit j (gates r,z,n stacked at 0,H,2H)
  float ebi0 = enc_bih[j], ebi1 = enc_bih[HID + j], ebi2 = enc_bih[2 * HID + j];
  float ebh0 = enc_bhh[j], ebh1 = enc_bhh[HID + j], ebh2 = enc_bhh[2 * HID + j];
  float dbi0 = dec_bih[j], dbi1 = dec_bih[HID + j], dbi2 = dec_bih[2 * HID + j];
  float dbh0 = dec_bhh[j], dbh1 = dec_bhh[HID + j], dbh2 = dec_bhh[2 * HID + j];

  if (b == 0 && tid == 0) out[0] = 1.0f;  // SOS

  // ---- P0: stage this block's 24 encoder GRU rows into LDS (f32) ----
  {
    float* wenc = (float*)dynls;
    for (int rr = 0; rr < 24; ++rr) {      // rr = q*6 + g, g in {ih r,z,n, hh r,z,n}
      const int qq = rr / 6, g = rr % 6;
      const int jj = 4 * b + qq;
      const float* src = (g < 3)
          ? (enc_wih + (size_t)(g * HID + jj) * HID)
          : (enc_whh + (size_t)((g - 3) * HID + jj) * HID);
      ((float4*)(wenc + rr * HID))[tid] = ((const float4*)src)[tid];
    }
  }
  __syncthreads();

  // ---- encoder: 256 sequential GRU steps, pure dataflow ----
  // h_t lives in ht[t&1] with tag t; h_0 = zeros tag 0 directly from memset.
  {
    const float* wq = (const float*)dynls + q * 6 * HID;
    // prologue: stage x0, ih-dots for t=0, prefetch x1
    float4 pf = ((const float4*)(enc_emb + (size_t)X[0] * HID))[tid];
    ((float4*)sx)[tid] = pf;
    __syncthreads();
    float ri0, ri1, ri2;
    dots3(wq, wq + HID, wq + 2 * HID, lane, sx, ri0, ri1, ri2);
    pf = ((const float4*)(enc_emb + (size_t)X[1] * HID))[tid];

    for (int t = 0; t < SRC_LEN; ++t) {
      gather_h(sh, ht + (size_t)(t & 1) * 1024, (unsigned)t, tid);
      __syncthreads();
      const float hold = sh[j];
      float rh0, rh1, rh2;
      dots3(wq + 3 * HID, wq + 4 * HID, wq + 5 * HID, lane, sh, rh0, rh1, rh2);
      const float hnew = gru_comb(ri0, ri1, ri2, rh0, rh1, rh2,
                                  ebi0, ebi1, ebi2, ebh0, ebh1, ebh2, hold);
      if (lane == 0)
        st_a64(&ht[(size_t)((t + 1) & 1) * 1024 + j],
               ((unsigned long long)(unsigned)(t + 1) << 32) | __float_as_uint(hnew));
      // overlap zone (propagation shadow): stage x_{t+1}, ih-dots(t+1), prefetch
      if (t + 1 < SRC_LEN) {
        ((float4*)sx)[tid] = pf;
        __syncthreads();
        dots3(wq, wq + HID, wq + 2 * HID, lane, sx, ri0, ri1, ri2);
        if (t + 2 < SRC_LEN)
          pf = ((const float4*)(enc_emb + (size_t)X[t + 2] * HID))[tid];
      }
    }
  }
  __syncthreads();   // all waves done reading enc weights before dynls reuse

  // ---- pre-decoder: gather h_enc (tag 256), hh-dots for t=0 ----
  gather_h(sh, ht, 256u, tid);   // parity 256&1 == 0
  __syncthreads();

  const float* dh0 = dec_whh + (size_t)j * HID;
  const float* dh1 = dec_whh + (size_t)(HID + j) * HID;
  const float* dh2 = dec_whh + (size_t)(2 * HID + j) * HID;
  const float* di0 = dec_wih + (size_t)j * HID;
  const float* di1 = dec_wih + (size_t)(HID + j) * HID;
  const float* di2 = dec_wih + (size_t)(2 * HID + j) * HID;

  float rh0, rh1, rh2, hold;
  dots3(dh0, dh1, dh2, lane, sh, rh0, rh1, rh2);
  hold = sh[j];
  unsigned tok = 1u;   // SOS
  float4 xf = ((const float4*)(dec_emb + (size_t)tok * HID))[tid];
  const float lbias = (tid < RPB) ? lin_b[vbase + tid] : 0.f;

  // ---- P1: fp8 (e4m3fn, x256) transposed copy of this block's lin_w rows ----
  // layout: lq[k8][r] u64 = 8 fp8 (k = 8*k8..8*k8+7) of row vbase+r.
  {
    unsigned* lq32 = (unsigned*)dynls;
    const int k8 = tid >> 1, kh = tid & 1;   // thread covers cols 4*tid..4*tid+3
    for (int rr = 0; rr < RPB; ++rr) {
      float4 f = ((const float4*)(lin_w + (size_t)(vbase + rr) * HID))[tid];
      f.x *= 256.f; f.y *= 256.f; f.z *= 256.f; f.w *= 256.f;
      lq32[(size_t)(k8 * 128 + rr) * 2 + kh] = fp8x4_enc(f);
    }
    unsigned long long* lqz = (unsigned long long*)dynls;
    for (int i = tid; i < 3 * 128; i += NTHR)        // zero pad rows 125..127
      lqz[(i / 3) * 128 + 125 + (i % 3)] = 0ull;
  }
  __syncthreads();

  // ---- greedy decoder, dataflow ----
  // h_dec(t): tag 257+t, parity (t+1)&1.  sum/key(t): tag t+1, parity (t+1)&1.
  bool done = false;
  const unsigned long long* lq = (const unsigned long long*)dynls;

  for (int t = 0; t <= MAX_LEN; ++t) {
    if (t > 0) {
      // gather per-block sums + keys of step t-1 (tag t)
      const unsigned tg = (unsigned)t;
      const int par = t & 1;
      const unsigned long long* ps = sums + (size_t)par * 256 + tid;
      const unsigned long long* pa = keya + (size_t)par * 256 + tid;
      const unsigned long long* pb = keyb + (size_t)par * 256 + tid;
      unsigned long long vs = ld_a64(ps), va = ld_a64(pa), vb = ld_a64(pb);
      while ((((unsigned)(vs >> 32)) != tg) | (((unsigned)(va >> 32)) != tg) |
             (((unsigned)(vb >> 32)) != tg)) {
        __builtin_amdgcn_s_sleep(1);
        if (((unsigned)(vs >> 32)) != tg) vs = ld_a64(ps);
        if (((unsigned)(va >> 32)) != tg) va = ld_a64(pa);
        if (((unsigned)(vb >> 32)) != tg) vb = ld_a64(pb);
      }
      float sv = __uint_as_float((unsigned)vs);
      unsigned long long kv =
          ((unsigned long long)(unsigned)va << 32) | (unsigned)vb;
#pragma unroll
      for (int off = 32; off; off >>= 1) {
        sv += __shfl_xor(sv, off);
        const unsigned long long ko = __shfl_xor(kv, off);
        kv = (ko > kv) ? ko : kv;
      }
      if (lane == 0) { redS[q] = sv; sbk[q] = kv; }
      __syncthreads();
      const float stot = (redS[0] + redS[1]) + (redS[2] + redS[3]);
      const unsigned long long k01 = sbk[0] > sbk[1] ? sbk[0] : sbk[1];
      const unsigned long long k23 = sbk[2] > sbk[3] ? sbk[2] : sbk[3];
      const unsigned long long key = k01 > k23 ? k01 : k23;

      const unsigned nxt = 0xFFFFFFFFu - (unsigned)(key & 0xFFFFFFFFull);
      const unsigned ntok = done ? tok : nxt;
      xf = ((const float4*)(dec_emb + (size_t)ntok * HID))[tid];
      if (b == 0 && tid == 0) out[t] = done ? (float)EOS_TOK : (float)nxt;
      if (tid < RPB) {
        float p = 0.f;
        if (!done) p = expb[vbase + tid] * (1.f / stot);
        probs[(size_t)(t - 1) * VOC + vbase + tid] = p;
      }
      tok = ntok;
      done = done || (nxt == EOS_TOK);
    }
    if (t == MAX_LEN) break;
    if (done) {
      for (int s = t; s < MAX_LEN; ++s) {
        if (tid < RPB) probs[(size_t)s * VOC + vbase + tid] = 0.f;
        if (b == 0 && tid == 0) out[s + 1] = (float)EOS_TOK;
      }
      break;
    }

    // ---- phase A: GRU cell on x = relu(dec_emb[tok]); hh-dots precomputed ----
    {
      float4 f = xf;
      f.x = fmaxf(f.x, 0.f); f.y = fmaxf(f.y, 0.f);
      f.z = fmaxf(f.z, 0.f); f.w = fmaxf(f.w, 0.f);
      ((float4*)sx)[tid] = f;
    }
    __syncthreads();
    float ai0, ai1, ai2;
    dots3(di0, di1, di2, lane, sx, ai0, ai1, ai2);
    const float hnew = gru_comb(ai0, ai1, ai2, rh0, rh1, rh2,
                                dbi0, dbi1, dbi2, dbh0, dbh1, dbh2, hold);
    if (lane == 0)
      st_a64(&ht[(size_t)((t + 1) & 1) * 1024 + j],
             ((unsigned long long)(unsigned)(257 + t) << 32) | __float_as_uint(hnew));

    // ---- phase B: gather h_dec(t), logits over this block's 125 rows ----
    gather_h(sh, ht + (size_t)((t + 1) & 1) * 1024, (unsigned)(257 + t), tid);
    if (tid < 128) slog[tid] = -1e30f;
    __syncthreads();

    {
      // two threads per row: r = tid&127 handles k-half kh = tid>>7
      const int r = tid & 127, kh = tid >> 7;
      const unsigned long long* wp = lq + ((size_t)kh << 13) + r;  // kh*64*128
      const float* hp = sh + (kh << 9);
      float acc = 0.f;
#pragma unroll 8
      for (int jj = 0; jj < 64; ++jj) {
        const unsigned long long w = wp[(size_t)jj << 7];
        const float4 h0 = *(const float4*)(hp + (jj << 3));
        const float4 h1 = *(const float4*)(hp + (jj << 3) + 4);
        const unsigned lo = (unsigned)w, hi = (unsigned)(w >> 32);
#if USE_HW_FP8
        const v2f f01 = __builtin_amdgcn_cvt_pk_f32_fp8(lo, false);
        const v2f f23 = __builtin_amdgcn_cvt_pk_f32_fp8(lo, true);
        const v2f f45 = __builtin_amdgcn_cvt_pk_f32_fp8(hi, false);
        const v2f f67 = __builtin_amdgcn_cvt_pk_f32_fp8(hi, true);
        acc += f01.x * h0.x + f01.y * h0.y + f23.x * h0.z + f23.y * h0.w
             + f45.x * h1.x + f45.y * h1.y + f67.x * h1.z + f67.y * h1.w;
#else
        acc += fp8_dec1(lo) * h0.x + fp8_dec1(lo >> 8) * h0.y
             + fp8_dec1(lo >> 16) * h0.z + fp8_dec1(lo >> 24) * h0.w
             + fp8_dec1(hi) * h1.x + fp8_dec1(hi >> 8) * h1.y
             + fp8_dec1(hi >> 16) * h1.z + fp8_dec1(hi >> 24) * h1.w;
#endif
      }
      spart[tid] = acc;
    }
    __syncthreads();
    float e = 0.f;
    if (tid < RPB) {
      const float logit = (spart[tid] + spart[tid + 128]) * (1.f / 256.f) + lbias;
      e = __expf(logit);
      expb[vbase + tid] = e;
      slog[tid] = logit;
    }
    float s = e;
#pragma unroll
    for (int off = 32; off; off >>= 1) s += __shfl_xor(s, off);
    if (lane == 0) redS[q] = s;
    __syncthreads();

    // block-local max of approx logits
    if (q == 0) {
      float m = fmaxf(slog[lane], slog[lane + 64]);
#pragma unroll
      for (int off = 32; off; off >>= 1) m = fmaxf(m, __shfl_xor(m, off));
      if (lane == 0) sbmax = m;
    }
    __syncthreads();
    {
      const bool cand = (tid < RPB) && (slog[tid] >= sbmax - 4e-3f);
      const unsigned long long bal = __ballot(cand);
      if (lane == 0 && q < 2) sball[q] = bal;
    }
    __syncthreads();
    // exact-f32 re-check of candidate rows -> per-block best key
    {
      unsigned long long m0 = sball[0], m1 = sball[1];
      unsigned long long bestk = 0ull;
      int c = 0;
      while (m0 | m1) {
        int r;
        if (m0) { r = __ffsll(m0) - 1; m0 &= m0 - 1; }
        else    { r = 64 + __ffsll(m1) - 1; m1 &= m1 - 1; }
        if ((c & 3) == q) {
          const int v = vbase + r;
          const float* wr = lin_w + (size_t)v * HID;
          float acc = 0.f;
#pragma unroll
          for (int i = 0; i < 4; ++i) {
            const float4 f = *(const float4*)(wr + 4 * lane + 256 * i);
            const float4 hv = *(const float4*)(sh + 4 * lane + 256 * i);
            acc += f.x * hv.x + f.y * hv.y + f.z * hv.z + f.w * hv.w;
          }
#pragma unroll
          for (int off = 32; off; off >>= 1) acc += __shfl_xor(acc, off);
          const float logit = acc + lin_b[v];
          const unsigned u = __float_as_uint(logit);
          const unsigned sb = (u & 0x80000000u) ? ~u : (u | 0x80000000u);
          const unsigned long long k =
              ((unsigned long long)sb << 32) | (unsigned long long)(0xFFFFFFFFu - (unsigned)v);
          if (k > bestk) bestk = k;
        }
        ++c;
      }
      if (lane == 0) sbk[q] = bestk;   // bestk is wave-uniform
    }
    __syncthreads();
    if (tid == 0) {
      const unsigned long long k01 = sbk[0] > sbk[1] ? sbk[0] : sbk[1];
      const unsigned long long k23 = sbk[2] > sbk[3] ? sbk[2] : sbk[3];
      const unsigned long long bk = k01 > k23 ? k01 : k23;
      const float st4 = (redS[0] + redS[1]) + (redS[2] + redS[3]);
      const unsigned long long tgh = (unsigned long long)(unsigned)(t + 1) << 32;
      const size_t par = (size_t)((t + 1) & 1) * 256;
      st_a64(&sums[par + b], tgh | __float_as_uint(st4));
      st_a64(&keya[par + b], tgh | (unsigned)(bk >> 32));
      st_a64(&keyb[par + b], tgh | (unsigned)bk);
    }
    // overlap zone (propagation shadow): hh-dots for step t+1 from sh
    dots3(dh0, dh1, dh2, lane, sh, rh0, rh1, rh2);
    hold = sh[j];
  }
}

extern "C" void kernel_launch(void* const* d_in, const int* in_sizes, int n_in,
                              void* d_out, int out_size, void* d_ws, size_t ws_size,
                              hipStream_t stream) {
  const int* X = (const int*)d_in[0];
  const float* enc_emb = (const float*)d_in[1];
  const float* enc_wih = (const float*)d_in[2];
  const float* enc_whh = (const float*)d_in[3];
  const float* enc_bih = (const float*)d_in[4];
  const float* enc_bhh = (const float*)d_in[5];
  const float* dec_emb = (const float*)d_in[6];
  const float* dec_wih = (const float*)d_in[7];
  const float* dec_whh = (const float*)d_in[8];
  const float* dec_bih = (const float*)d_in[9];
  const float* dec_bhh = (const float*)d_in[10];
  const float* lin_w = (const float*)d_in[11];
  const float* lin_b = (const float*)d_in[12];
  float* out = (float*)d_out;
  char* ws = (char*)d_ws;

  hipMemsetAsync(d_ws, 0, WS_ZERO, stream);
  void* args[] = { &X, &enc_emb, &enc_wih, &enc_whh, &enc_bih, &enc_bhh,
                   &dec_emb, &dec_wih, &dec_whh, &dec_bih, &dec_bhh,
                   &lin_w, &lin_b, &out, &ws };
  hipLaunchCooperativeKernel((void*)seq2seq_kernel, dim3(NBLK), dim3(NTHR),
                             args, 0, stream);
}